// Round 1
// baseline (2438.565 us; speedup 1.0000x reference)
//
#include <hip/hip_runtime.h>
#include <cstdint>
#include <cstddef>

// ---------------------------------------------------------------------------
// SSLModel: dual-branch GCN (128->512->1024->2048) + global max pool + MLP.
// Round 1: correct fp32 implementation.
//   GCN rewrite: A_hat (X W) == (A_hat X) W  -> aggregate FIRST (cheaper dim).
// ---------------------------------------------------------------------------

#define NN 10000     // nodes
#define NE 160000    // edges
#define NG 128       // graphs

// ---------------- small utility kernels ----------------

__global__ void k_fill_i32(int* __restrict__ p, int v, int n) {
  int i = blockIdx.x * blockDim.x + threadIdx.x;
  if (i < n) p[i] = v;
}

__global__ void k_count(const int* __restrict__ dst, int* __restrict__ cnt, int e) {
  int i = blockIdx.x * blockDim.x + threadIdx.x;
  if (i < e) atomicAdd(&cnt[dst[i]], 1);
}

// dinv[i] = rsqrt(in_degree + 1 self loop)
__global__ void k_dinv(const int* __restrict__ cnt, float* __restrict__ dinv, int n) {
  int i = blockIdx.x * blockDim.x + threadIdx.x;
  if (i < n) dinv[i] = rsqrtf((float)cnt[i] + 1.0f);
}

// exclusive scan of cnt[0..n) -> row_ptr[0..n], cursor copy. single block, 256 thr.
__global__ void k_scan(const int* __restrict__ cnt, int* __restrict__ row_ptr,
                       int* __restrict__ cursor, int n) {
  __shared__ int part[256];
  __shared__ int partex[257];
  int t = threadIdx.x;
  const int CH = (n + 255) / 256;
  int base = t * CH;
  int s = 0;
  for (int i = 0; i < CH; ++i) {
    int idx = base + i;
    if (idx < n) s += cnt[idx];
  }
  part[t] = s;
  __syncthreads();
  if (t == 0) {
    int acc = 0;
    for (int i = 0; i < 256; ++i) { partex[i] = acc; acc += part[i]; }
    partex[256] = acc;
  }
  __syncthreads();
  int acc = partex[t];
  for (int i = 0; i < CH; ++i) {
    int idx = base + i;
    if (idx < n) {
      row_ptr[idx] = acc;
      cursor[idx]  = acc;
      acc += cnt[idx];
    }
  }
  if (t == 255) row_ptr[n] = partex[256];
}

// build CSR (grouped by dst): csr_src[pos], csr_w[pos] = dinv[src]*dinv[dst]
__global__ void k_scatter(const int* __restrict__ ei, const float* __restrict__ dinv,
                          int* __restrict__ cursor, int* __restrict__ csr_src,
                          float* __restrict__ csr_w, int e) {
  int i = blockIdx.x * blockDim.x + threadIdx.x;
  if (i >= e) return;
  int s = ei[i];
  int d = ei[NE + i];
  int pos = atomicAdd(&cursor[d], 1);
  csr_src[pos] = s;
  csr_w[pos] = dinv[s] * dinv[d];
}

// out[i,f] = dinv[i]^2 * in[i,f] + sum_{e: dst=i} w_e * in[src_e, f]
// grid: (NN, F/blockDim), block: 128 or 256
__global__ void k_agg(const float* __restrict__ in, float* __restrict__ out,
                      const int* __restrict__ row_ptr, const int* __restrict__ csr_src,
                      const float* __restrict__ csr_w, const float* __restrict__ dinv,
                      int F) {
  int node = blockIdx.x;
  int f = blockIdx.y * blockDim.x + threadIdx.x;
  if (f >= F) return;
  float di = dinv[node];
  float acc = di * di * in[(size_t)node * F + f];
  int e0 = row_ptr[node], e1 = row_ptr[node + 1];
  for (int e = e0; e < e1; ++e) {
    int s = csr_src[e];
    float w = csr_w[e];
    acc = fmaf(w, in[(size_t)s * F + f], acc);
  }
  out[(size_t)node * F + f] = acc;
}

// ---------------- fp32 tiled GEMM: C = A[MxK] * B[KxN] + bias (+relu/+sigmoid copy)
// 64x64 tile, BK=32, 256 threads, 4x4 per-thread micro-tile.
template <bool RELU, bool SIG>
__global__ __launch_bounds__(256) void k_gemm(
    const float* __restrict__ A, const float* __restrict__ B,
    const float* __restrict__ bias, float* __restrict__ C,
    int M, int N, int K, float* __restrict__ C2) {
  __shared__ float As[32][64];  // [k][m]
  __shared__ float Bs[32][64];  // [k][n]

  int t = threadIdx.x;
  int tx = t & 15, ty = t >> 4;
  int bm = blockIdx.y * 64, bn = blockIdx.x * 64;

  float acc[4][4] = {};

  int arow0 = t >> 3;           // [0,32)
  int ak4 = (t & 7) * 4;        // [0,28]
  int brow0 = t >> 4;           // [0,16)
  int bn4 = (t & 15) * 4;       // [0,60]
  const bool n4al = (N & 3) == 0;

  for (int k0 = 0; k0 < K; k0 += 32) {
    // A tile: 64 rows x 32 cols (K multiple of 32 always here)
#pragma unroll
    for (int c = 0; c < 2; ++c) {
      int row = arow0 + c * 32;
      int gr = bm + row;
      float4 v = make_float4(0.f, 0.f, 0.f, 0.f);
      if (gr < M) v = *(const float4*)&A[(size_t)gr * K + k0 + ak4];
      As[ak4 + 0][row] = v.x;
      As[ak4 + 1][row] = v.y;
      As[ak4 + 2][row] = v.z;
      As[ak4 + 3][row] = v.w;
    }
    // B tile: 32 rows x 64 cols
#pragma unroll
    for (int c = 0; c < 2; ++c) {
      int row = brow0 + c * 16;
      int gc = bn + bn4;
      const float* bp = &B[(size_t)(k0 + row) * N + gc];
      float4 v;
      if (n4al && gc + 3 < N) {
        v = *(const float4*)bp;
      } else {
        v = make_float4(0.f, 0.f, 0.f, 0.f);
        if (gc < N) v.x = bp[0];
        if (gc + 1 < N) v.y = bp[1];
        if (gc + 2 < N) v.z = bp[2];
        if (gc + 3 < N) v.w = bp[3];
      }
      *(float4*)&Bs[row][bn4] = v;
    }
    __syncthreads();

#pragma unroll
    for (int kk = 0; kk < 32; ++kk) {
      float4 a = *(const float4*)&As[kk][ty * 4];
      float4 b = *(const float4*)&Bs[kk][tx * 4];
      float av[4] = {a.x, a.y, a.z, a.w};
      float bv[4] = {b.x, b.y, b.z, b.w};
#pragma unroll
      for (int i = 0; i < 4; ++i)
#pragma unroll
        for (int j = 0; j < 4; ++j)
          acc[i][j] = fmaf(av[i], bv[j], acc[i][j]);
    }
    __syncthreads();
  }

  int r0 = bm + ty * 4, c0 = bn + tx * 4;
#pragma unroll
  for (int i = 0; i < 4; ++i) {
    int r = r0 + i;
    if (r < M) {
#pragma unroll
      for (int j = 0; j < 4; ++j) {
        int c = c0 + j;
        if (c < N) {
          float v = acc[i][j] + bias[c];
          if (RELU) v = fmaxf(v, 0.f);
          C[(size_t)r * N + c] = v;
          if (SIG) C2[(size_t)r * N + c] = 1.0f / (1.0f + __expf(-v));
        }
      }
    }
  }
}

// seg[g] = lower_bound(batch, g), g in [0, G]
__global__ void k_segptr(const int* __restrict__ batch, int* __restrict__ seg,
                         int n, int G) {
  int g = blockIdx.x * blockDim.x + threadIdx.x;
  if (g > G) return;
  int lo = 0, hi = n;
  while (lo < hi) {
    int mid = (lo + hi) >> 1;
    if (batch[mid] < g) lo = mid + 1;
    else hi = mid;
  }
  seg[g] = lo;
}

// P[g,f] = max over nodes in segment (post-relu, >=0) else 0. grid (NG, F/256)
__global__ void k_pool(const float* __restrict__ act, const int* __restrict__ seg,
                       float* __restrict__ P, int F) {
  int g = blockIdx.x;
  int f = blockIdx.y * blockDim.x + threadIdx.x;
  if (f >= F) return;
  int i0 = seg[g], i1 = seg[g + 1];
  float m = 0.0f;
  for (int i = i0; i < i1; ++i) m = fmaxf(m, act[(size_t)i * F + f]);
  P[(size_t)g * F + f] = m;
}

__global__ void k_add(const float* __restrict__ a, const float* __restrict__ b,
                      float* __restrict__ z, int n) {
  int i = blockIdx.x * blockDim.x + threadIdx.x;
  if (i < n) z[i] = a[i] + b[i];
}

// ---------------- branch driver ----------------

static void run_branch(const float* x, const int* ei, const int* batch,
                       const float* W1, const float* b1,
                       const float* W2, const float* b2,
                       const float* W3, const float* b3,
                       float* P, float* ACT, float* AGG, float* dinv,
                       int* cnt, int* row_ptr, int* cursor,
                       int* csr_src, float* csr_w, int* seg,
                       hipStream_t stream) {
  k_fill_i32<<<(NN + 255) / 256, 256, 0, stream>>>(cnt, 0, NN);
  k_count<<<(NE + 255) / 256, 256, 0, stream>>>(ei + NE, cnt, NE);
  k_dinv<<<(NN + 255) / 256, 256, 0, stream>>>(cnt, dinv, NN);
  k_scan<<<1, 256, 0, stream>>>(cnt, row_ptr, cursor, NN);
  k_scatter<<<(NE + 255) / 256, 256, 0, stream>>>(ei, dinv, cursor, csr_src, csr_w, NE);

  // L1: t1 = A_hat x (F=128); o1 = t1 @ W1 + b1 (no relu)
  k_agg<<<dim3(NN, 1), 128, 0, stream>>>(x, AGG, row_ptr, csr_src, csr_w, dinv, 128);
  k_gemm<false, false><<<dim3(512 / 64, (NN + 63) / 64), 256, 0, stream>>>(
      AGG, W1, b1, ACT, NN, 512, 128, nullptr);

  // L2: t2 = A_hat o1 (F=512); o2 = relu(t2 @ W2 + b2)
  k_agg<<<dim3(NN, 2), 256, 0, stream>>>(ACT, AGG, row_ptr, csr_src, csr_w, dinv, 512);
  k_gemm<true, false><<<dim3(1024 / 64, (NN + 63) / 64), 256, 0, stream>>>(
      AGG, W2, b2, ACT, NN, 1024, 512, nullptr);

  // L3: t3 = A_hat o2 (F=1024); o3 = relu(t3 @ W3 + b3)
  k_agg<<<dim3(NN, 4), 256, 0, stream>>>(ACT, AGG, row_ptr, csr_src, csr_w, dinv, 1024);
  k_gemm<true, false><<<dim3(2048 / 64, (NN + 63) / 64), 256, 0, stream>>>(
      AGG, W3, b3, ACT, NN, 2048, 1024, nullptr);

  // pool
  k_segptr<<<1, 256, 0, stream>>>(batch, seg, NN, NG);
  k_pool<<<dim3(NG, 2048 / 256), 256, 0, stream>>>(ACT, seg, P, 2048);
}

// ---------------- entry ----------------

extern "C" void kernel_launch(void* const* d_in, const int* in_sizes, int n_in,
                              void* d_out, int out_size, void* d_ws, size_t ws_size,
                              hipStream_t stream) {
  const float* x_s = (const float*)d_in[0];
  const float* x_t = (const float*)d_in[1];
  const int* ei_s = (const int*)d_in[2];
  const int* ei_t = (const int*)d_in[3];
  const int* xs_batch = (const int*)d_in[4];
  const int* xt_batch = (const int*)d_in[5];
  const float* W_enc1 = (const float*)d_in[6];
  const float* b_enc1 = (const float*)d_in[7];
  const float* W_enc2 = (const float*)d_in[8];
  const float* b_enc2 = (const float*)d_in[9];
  const float* W_r1g1 = (const float*)d_in[10];
  const float* b_r1g1 = (const float*)d_in[11];
  const float* W_r1g2 = (const float*)d_in[12];
  const float* b_r1g2 = (const float*)d_in[13];
  const float* W_r2g1 = (const float*)d_in[14];
  const float* b_r2g1 = (const float*)d_in[15];
  const float* W_r2g2 = (const float*)d_in[16];
  const float* b_r2g2 = (const float*)d_in[17];
  const float* W_l1 = (const float*)d_in[18];
  const float* b_l1 = (const float*)d_in[19];
  const float* W_l2 = (const float*)d_in[20];
  const float* b_l2 = (const float*)d_in[21];

  float* out = (float*)d_out;

  // workspace carve-up (256B aligned)
  char* ws = (char*)d_ws;
  size_t off = 0;
  auto carve = [&](size_t bytes) {
    char* p = ws + off;
    off = (off + bytes + 255) & ~(size_t)255;
    return p;
  };
  float* ACT    = (float*)carve((size_t)NN * 2048 * 4);
  float* AGG    = (float*)carve((size_t)NN * 1024 * 4);
  float* P_s    = (float*)carve((size_t)NG * 2048 * 4);
  float* P_t    = (float*)carve((size_t)NG * 2048 * 4);
  float* Z      = (float*)carve((size_t)NG * 2048 * 4);
  float* ZZ     = (float*)carve((size_t)NG * 1024 * 4);
  float* dinv   = (float*)carve((size_t)NN * 4);
  int* cnt      = (int*)carve((size_t)NN * 4);
  int* row_ptr  = (int*)carve((size_t)(NN + 1) * 4);
  int* cursor   = (int*)carve((size_t)NN * 4);
  int* csr_src  = (int*)carve((size_t)NE * 4);
  float* csr_w  = (float*)carve((size_t)NE * 4);
  int* seg      = (int*)carve((size_t)(NG + 1) * 4);
  (void)ws_size; (void)n_in; (void)in_sizes; (void)out_size;

  // branch 1 (source), branch 2 (target) — sequential, reusing ACT/AGG/CSR
  run_branch(x_s, ei_s, xs_batch, W_enc1, b_enc1, W_r1g1, b_r1g1, W_r1g2, b_r1g2,
             P_s, ACT, AGG, dinv, cnt, row_ptr, cursor, csr_src, csr_w, seg, stream);
  run_branch(x_t, ei_t, xt_batch, W_enc2, b_enc2, W_r2g1, b_r2g1, W_r2g2, b_r2g2,
             P_t, ACT, AGG, dinv, cnt, row_ptr, cursor, csr_src, csr_w, seg, stream);

  // Z = P_s + P_t  [128, 2048]
  k_add<<<(NG * 2048 + 255) / 256, 256, 0, stream>>>(P_s, P_t, Z, NG * 2048);

  // MLP head: ZZ = relu(Z @ W_l1 + b_l1)  [128, 1024]
  k_gemm<true, false><<<dim3(1024 / 64, (NG + 63) / 64), 256, 0, stream>>>(
      Z, W_l1, b_l1, ZZ, NG, 1024, 2048, nullptr);

  // logits = ZZ @ W_l2 + b_l2  [128, 1317]; out[0]=logits, out[1]=sigmoid
  const int OUTN = 1317;
  k_gemm<false, true><<<dim3((OUTN + 63) / 64, (NG + 63) / 64), 256, 0, stream>>>(
      ZZ, W_l2, b_l2, out, NG, OUTN, 1024, out + (size_t)NG * OUTN);
}

// Round 2
// 1290.034 us; speedup vs baseline: 1.8903x; 1.8903x over previous
//
#include <hip/hip_runtime.h>
#include <cstdint>
#include <cstddef>

// ---------------------------------------------------------------------------
// SSLModel: dual-branch GCN + global max pool + MLP head.
// Round 2: split-bf16 MFMA GEMMs (x = hi + lo; x*y ~ hh + hl + lh), fused
// aggregate+split, conflict-free fragment-subtile LDS layout.
// ---------------------------------------------------------------------------

#define NN 10000     // nodes
#define NNP 10112    // nodes padded to 128
#define NE 160000    // edges
#define NG 128       // graphs

typedef short bf16x8 __attribute__((ext_vector_type(8)));
typedef float f32x4 __attribute__((ext_vector_type(4)));

__device__ __forceinline__ unsigned short f2bf(float x) {
  unsigned u = __float_as_uint(x);
  u += 0x7FFFu + ((u >> 16) & 1u);   // round-to-nearest-even (finite inputs)
  return (unsigned short)(u >> 16);
}
__device__ __forceinline__ float bf2f(unsigned short h) {
  return __uint_as_float(((unsigned)h) << 16);
}

#define GLOAD_LDS16(gp, lp)                                                  \
  __builtin_amdgcn_global_load_lds(                                          \
      (const __attribute__((address_space(1))) void*)(gp),                   \
      (__attribute__((address_space(3))) void*)(lp), 16, 0, 0)

// ---------------- CSR build ----------------

__global__ void k_fill_i32(int* __restrict__ p, int v, int n) {
  int i = blockIdx.x * blockDim.x + threadIdx.x;
  if (i < n) p[i] = v;
}

__global__ void k_count(const int* __restrict__ dst, int* __restrict__ cnt, int e) {
  int i = blockIdx.x * blockDim.x + threadIdx.x;
  if (i < e) atomicAdd(&cnt[dst[i]], 1);
}

__global__ void k_dinv(const int* __restrict__ cnt, float* __restrict__ dinv, int n) {
  int i = blockIdx.x * blockDim.x + threadIdx.x;
  if (i < n) dinv[i] = rsqrtf((float)cnt[i] + 1.0f);
}

__global__ void k_scan(const int* __restrict__ cnt, int* __restrict__ row_ptr,
                       int* __restrict__ cursor, int n) {
  __shared__ int part[256];
  __shared__ int partex[257];
  int t = threadIdx.x;
  const int CH = (n + 255) / 256;
  int base = t * CH;
  int s = 0;
  for (int i = 0; i < CH; ++i) {
    int idx = base + i;
    if (idx < n) s += cnt[idx];
  }
  part[t] = s;
  __syncthreads();
  if (t == 0) {
    int acc = 0;
    for (int i = 0; i < 256; ++i) { partex[i] = acc; acc += part[i]; }
    partex[256] = acc;
  }
  __syncthreads();
  int acc = partex[t];
  for (int i = 0; i < CH; ++i) {
    int idx = base + i;
    if (idx < n) {
      row_ptr[idx] = acc;
      cursor[idx]  = acc;
      acc += cnt[idx];
    }
  }
  if (t == 255) row_ptr[n] = partex[256];
}

__global__ void k_scatter(const int* __restrict__ ei, const float* __restrict__ dinv,
                          int* __restrict__ cursor, int* __restrict__ csr_src,
                          float* __restrict__ csr_w, int e) {
  int i = blockIdx.x * blockDim.x + threadIdx.x;
  if (i >= e) return;
  int s = ei[i];
  int d = ei[NE + i];
  int pos = atomicAdd(&cursor[d], 1);
  csr_src[pos] = s;
  csr_w[pos] = dinv[s] * dinv[d];
}

// ---------------- fused aggregate + bf16 split ----------------
// Ah/Al[node][f] (bf16 hi/lo of A_hat @ in), rows >= NN zeroed.
// grid: (NNP, 1); block covers F4 = F/4 lanes of float4.
__global__ void k_aggsplit(const float* __restrict__ in,
                           unsigned short* __restrict__ Ah,
                           unsigned short* __restrict__ Al,
                           const int* __restrict__ row_ptr,
                           const int* __restrict__ csr_src,
                           const float* __restrict__ csr_w,
                           const float* __restrict__ dinv, int F4) {
  int node = blockIdx.x;
  int f4 = blockIdx.y * blockDim.x + threadIdx.x;
  if (f4 >= F4) return;
  size_t o = (size_t)node * F4 + f4;
  ushort4* Ah4 = (ushort4*)Ah;
  ushort4* Al4 = (ushort4*)Al;
  if (node >= NN) {
    Ah4[o] = make_ushort4(0, 0, 0, 0);
    Al4[o] = make_ushort4(0, 0, 0, 0);
    return;
  }
  const float4* inp = (const float4*)in;
  float di = dinv[node];
  float sw = di * di;
  float4 v = inp[o];
  float4 acc;
  acc.x = sw * v.x; acc.y = sw * v.y; acc.z = sw * v.z; acc.w = sw * v.w;
  int e0 = row_ptr[node], e1 = row_ptr[node + 1];
  for (int e = e0; e < e1; ++e) {
    int s = csr_src[e];
    float w = csr_w[e];
    float4 u = inp[(size_t)s * F4 + f4];
    acc.x = fmaf(w, u.x, acc.x);
    acc.y = fmaf(w, u.y, acc.y);
    acc.z = fmaf(w, u.z, acc.z);
    acc.w = fmaf(w, u.w, acc.w);
  }
  ushort4 h, l;
  h.x = f2bf(acc.x); l.x = f2bf(acc.x - bf2f(h.x));
  h.y = f2bf(acc.y); l.y = f2bf(acc.y - bf2f(h.y));
  h.z = f2bf(acc.z); l.z = f2bf(acc.z - bf2f(h.z));
  h.w = f2bf(acc.w); l.w = f2bf(acc.w - bf2f(h.w));
  Ah4[o] = h;
  Al4[o] = l;
}

// ---------------- weight transpose + split: W[K][N] -> Wt_hi/lo [N][K] ----
__global__ __launch_bounds__(256) void k_wsplit(const float* __restrict__ W,
                                                unsigned short* __restrict__ Ht,
                                                unsigned short* __restrict__ Lt,
                                                int K, int N) {
  __shared__ float tile[32][33];
  int nb = blockIdx.x * 32, kb = blockIdx.y * 32;
  int tx = threadIdx.x & 31, ty = threadIdx.x >> 5;
#pragma unroll
  for (int r = ty; r < 32; r += 8)
    tile[r][tx] = W[(size_t)(kb + r) * N + nb + tx];
  __syncthreads();
#pragma unroll
  for (int r = ty; r < 32; r += 8) {
    float x = tile[tx][r];  // = W[kb+tx][nb+r]
    unsigned short h = f2bf(x);
    unsigned short lo = f2bf(x - bf2f(h));
    size_t o = (size_t)(nb + r) * K + kb + tx;
    Ht[o] = h;
    Lt[o] = lo;
  }
}

// ---------------- split-bf16 MFMA GEMM ----------------
// C[M][N] = (Ah+Al)[M][K] @ (Bh+Bl)^T[N][K] (+bias, +relu)
// 128x128 tile, BK=32, 256 thr (4 waves 2x2), 16x16x32 bf16 MFMA, 3 MFMA/prod.
// LDS: 4 matrices x 8 subtiles x 1KiB; subtile = [kslot(4)][row16][8 bf16]
// so every stage chunk and every fragment read is a contiguous 1KiB
// full-wave access (conflict-free by construction).
template <bool RELU>
__global__ __launch_bounds__(256) void k_mgemm(
    const unsigned short* __restrict__ Ah, const unsigned short* __restrict__ Al,
    const unsigned short* __restrict__ Bh, const unsigned short* __restrict__ Bl,
    const float* __restrict__ bias, float* __restrict__ C,
    int M, int N, int K) {
  __shared__ char smem[32768];  // [Ah|Al|Bh|Bl] x 8KiB
  const int t = threadIdx.x;
  const int w = t >> 6, l = t & 63;
  const int bm = blockIdx.y * 128, bn = blockIdx.x * 128;
  const int wr = w >> 1, wc = w & 1;

  f32x4 acc[4][4] = {};

  // staging: wave w owns matrix w entirely (8 x 1KiB chunks)
  const unsigned short* g0 = (w == 0) ? Ah : (w == 1) ? Al : (w == 2) ? Bh : Bl;
  const int rb = (w < 2) ? bm : bn;
  const unsigned short* gbase = g0 + (size_t)(rb + (l & 15)) * K + ((l >> 4) * 8);
  char* sdst = smem + w * 8192 + l * 16;

  char* sA = smem + wr * 4096 + l * 16;           // A_hi frags; A_lo at +8192
  char* sB = smem + 16384 + wc * 4096 + l * 16;   // B_hi frags; B_lo at +8192

  for (int k0 = 0; k0 < K; k0 += 32) {
#pragma unroll
    for (int s = 0; s < 8; ++s)
      GLOAD_LDS16(gbase + (size_t)s * 16 * K + k0, sdst + s * 1024);
    __syncthreads();

    bf16x8 a[4][2], b[4][2];
#pragma unroll
    for (int i = 0; i < 4; ++i) {
      a[i][0] = *(const bf16x8*)(sA + i * 1024);
      a[i][1] = *(const bf16x8*)(sA + 8192 + i * 1024);
    }
#pragma unroll
    for (int j = 0; j < 4; ++j) {
      b[j][0] = *(const bf16x8*)(sB + j * 1024);
      b[j][1] = *(const bf16x8*)(sB + 8192 + j * 1024);
    }
#pragma unroll
    for (int i = 0; i < 4; ++i)
#pragma unroll
      for (int j = 0; j < 4; ++j) {
        acc[i][j] = __builtin_amdgcn_mfma_f32_16x16x32_bf16(a[i][0], b[j][0], acc[i][j], 0, 0, 0);
        acc[i][j] = __builtin_amdgcn_mfma_f32_16x16x32_bf16(a[i][0], b[j][1], acc[i][j], 0, 0, 0);
        acc[i][j] = __builtin_amdgcn_mfma_f32_16x16x32_bf16(a[i][1], b[j][0], acc[i][j], 0, 0, 0);
      }
    __syncthreads();
  }

  // epilogue: C/D layout (verified): col = lane&15, row = (lane>>4)*4 + reg
  const int r0 = bm + wr * 64 + ((l >> 4) << 2);
  const int c0 = bn + wc * 64 + (l & 15);
#pragma unroll
  for (int j = 0; j < 4; ++j) {
    const int col = c0 + j * 16;
    const float bv = bias[col];
#pragma unroll
    for (int i = 0; i < 4; ++i) {
      const int row = r0 + i * 16;
#pragma unroll
      for (int r = 0; r < 4; ++r) {
        int rr = row + r;
        if (rr < M) {
          float v = acc[i][j][r] + bv;
          if (RELU) v = fmaxf(v, 0.f);
          C[(size_t)rr * N + col] = v;
        }
      }
    }
  }
}

// ---------------- fp32 tiled GEMM (head only, M=128) ----------------
template <bool RELU, bool SIG>
__global__ __launch_bounds__(256) void k_gemm(
    const float* __restrict__ A, const float* __restrict__ B,
    const float* __restrict__ bias, float* __restrict__ C,
    int M, int N, int K, float* __restrict__ C2) {
  __shared__ float As[32][64];
  __shared__ float Bs[32][64];

  int t = threadIdx.x;
  int tx = t & 15, ty = t >> 4;
  int bm = blockIdx.y * 64, bn = blockIdx.x * 64;

  float acc[4][4] = {};

  int arow0 = t >> 3;
  int ak4 = (t & 7) * 4;
  int brow0 = t >> 4;
  int bn4 = (t & 15) * 4;
  const bool n4al = (N & 3) == 0;

  for (int k0 = 0; k0 < K; k0 += 32) {
#pragma unroll
    for (int c = 0; c < 2; ++c) {
      int row = arow0 + c * 32;
      int gr = bm + row;
      float4 v = make_float4(0.f, 0.f, 0.f, 0.f);
      if (gr < M) v = *(const float4*)&A[(size_t)gr * K + k0 + ak4];
      As[ak4 + 0][row] = v.x;
      As[ak4 + 1][row] = v.y;
      As[ak4 + 2][row] = v.z;
      As[ak4 + 3][row] = v.w;
    }
#pragma unroll
    for (int c = 0; c < 2; ++c) {
      int row = brow0 + c * 16;
      int gc = bn + bn4;
      const float* bp = &B[(size_t)(k0 + row) * N + gc];
      float4 v;
      if (n4al && gc + 3 < N) {
        v = *(const float4*)bp;
      } else {
        v = make_float4(0.f, 0.f, 0.f, 0.f);
        if (gc < N) v.x = bp[0];
        if (gc + 1 < N) v.y = bp[1];
        if (gc + 2 < N) v.z = bp[2];
        if (gc + 3 < N) v.w = bp[3];
      }
      *(float4*)&Bs[row][bn4] = v;
    }
    __syncthreads();

#pragma unroll
    for (int kk = 0; kk < 32; ++kk) {
      float4 a = *(const float4*)&As[kk][ty * 4];
      float4 b = *(const float4*)&Bs[kk][tx * 4];
      float av[4] = {a.x, a.y, a.z, a.w};
      float bv[4] = {b.x, b.y, b.z, b.w};
#pragma unroll
      for (int i = 0; i < 4; ++i)
#pragma unroll
        for (int j = 0; j < 4; ++j)
          acc[i][j] = fmaf(av[i], bv[j], acc[i][j]);
    }
    __syncthreads();
  }

  int r0 = bm + ty * 4, c0 = bn + tx * 4;
#pragma unroll
  for (int i = 0; i < 4; ++i) {
    int r = r0 + i;
    if (r < M) {
#pragma unroll
      for (int j = 0; j < 4; ++j) {
        int c = c0 + j;
        if (c < N) {
          float v = acc[i][j] + bias[c];
          if (RELU) v = fmaxf(v, 0.f);
          C[(size_t)r * N + c] = v;
          if (SIG) C2[(size_t)r * N + c] = 1.0f / (1.0f + __expf(-v));
        }
      }
    }
  }
}

// ---------------- pool / misc ----------------

__global__ void k_segptr(const int* __restrict__ batch, int* __restrict__ seg,
                         int n, int G) {
  int g = blockIdx.x * blockDim.x + threadIdx.x;
  if (g > G) return;
  int lo = 0, hi = n;
  while (lo < hi) {
    int mid = (lo + hi) >> 1;
    if (batch[mid] < g) lo = mid + 1;
    else hi = mid;
  }
  seg[g] = lo;
}

__global__ void k_pool(const float* __restrict__ act, const int* __restrict__ seg,
                       float* __restrict__ P, int F) {
  int g = blockIdx.x;
  int f = blockIdx.y * blockDim.x + threadIdx.x;
  if (f >= F) return;
  int i0 = seg[g], i1 = seg[g + 1];
  float m = 0.0f;
  for (int i = i0; i < i1; ++i) m = fmaxf(m, act[(size_t)i * F + f]);
  P[(size_t)g * F + f] = m;
}

__global__ void k_add(const float* __restrict__ a, const float* __restrict__ b,
                      float* __restrict__ z, int n) {
  int i = blockIdx.x * blockDim.x + threadIdx.x;
  if (i < n) z[i] = a[i] + b[i];
}

// ---------------- branch driver ----------------

static void run_branch(const float* x, const int* ei, const int* batch,
                       const unsigned short* W1h, const unsigned short* W1l, const float* b1,
                       const unsigned short* W2h, const unsigned short* W2l, const float* b2,
                       const unsigned short* W3h, const unsigned short* W3l, const float* b3,
                       float* P, float* ACT, unsigned short* Ah, unsigned short* Al,
                       float* dinv, int* cnt, int* row_ptr, int* cursor,
                       int* csr_src, float* csr_w, int* seg, hipStream_t stream) {
  k_fill_i32<<<(NN + 255) / 256, 256, 0, stream>>>(cnt, 0, NN);
  k_count<<<(NE + 255) / 256, 256, 0, stream>>>(ei + NE, cnt, NE);
  k_dinv<<<(NN + 255) / 256, 256, 0, stream>>>(cnt, dinv, NN);
  k_scan<<<1, 256, 0, stream>>>(cnt, row_ptr, cursor, NN);
  k_scatter<<<(NE + 255) / 256, 256, 0, stream>>>(ei, dinv, cursor, csr_src, csr_w, NE);

  // L1: A1 = split(A_hat x) [F=128]; ACT = A1 @ W1t + b1 (no relu) [NN,512]
  k_aggsplit<<<dim3(NNP, 1), 64, 0, stream>>>(x, Ah, Al, row_ptr, csr_src, csr_w, dinv, 32);
  k_mgemm<false><<<dim3(512 / 128, NNP / 128), 256, 0, stream>>>(
      Ah, Al, W1h, W1l, b1, ACT, NN, 512, 128);

  // L2: [F=512] -> relu GEMM [NN,1024]
  k_aggsplit<<<dim3(NNP, 1), 128, 0, stream>>>(ACT, Ah, Al, row_ptr, csr_src, csr_w, dinv, 128);
  k_mgemm<true><<<dim3(1024 / 128, NNP / 128), 256, 0, stream>>>(
      Ah, Al, W2h, W2l, b2, ACT, NN, 1024, 512);

  // L3: [F=1024] -> relu GEMM [NN,2048]
  k_aggsplit<<<dim3(NNP, 1), 256, 0, stream>>>(ACT, Ah, Al, row_ptr, csr_src, csr_w, dinv, 256);
  k_mgemm<true><<<dim3(2048 / 128, NNP / 128), 256, 0, stream>>>(
      Ah, Al, W3h, W3l, b3, ACT, NN, 2048, 1024);

  k_segptr<<<1, 256, 0, stream>>>(batch, seg, NN, NG);
  k_pool<<<dim3(NG, 2048 / 256), 256, 0, stream>>>(ACT, seg, P, 2048);
}

// ---------------- entry ----------------

extern "C" void kernel_launch(void* const* d_in, const int* in_sizes, int n_in,
                              void* d_out, int out_size, void* d_ws, size_t ws_size,
                              hipStream_t stream) {
  const float* x_s = (const float*)d_in[0];
  const float* x_t = (const float*)d_in[1];
  const int* ei_s = (const int*)d_in[2];
  const int* ei_t = (const int*)d_in[3];
  const int* xs_batch = (const int*)d_in[4];
  const int* xt_batch = (const int*)d_in[5];
  const float* W_enc1 = (const float*)d_in[6];
  const float* b_enc1 = (const float*)d_in[7];
  const float* W_enc2 = (const float*)d_in[8];
  const float* b_enc2 = (const float*)d_in[9];
  const float* W_r1g1 = (const float*)d_in[10];
  const float* b_r1g1 = (const float*)d_in[11];
  const float* W_r1g2 = (const float*)d_in[12];
  const float* b_r1g2 = (const float*)d_in[13];
  const float* W_r2g1 = (const float*)d_in[14];
  const float* b_r2g1 = (const float*)d_in[15];
  const float* W_r2g2 = (const float*)d_in[16];
  const float* b_r2g2 = (const float*)d_in[17];
  const float* W_l1 = (const float*)d_in[18];
  const float* b_l1 = (const float*)d_in[19];
  const float* W_l2 = (const float*)d_in[20];
  const float* b_l2 = (const float*)d_in[21];

  float* out = (float*)d_out;

  char* ws = (char*)d_ws;
  size_t off = 0;
  auto carve = [&](size_t bytes) {
    char* p = ws + off;
    off = (off + bytes + 255) & ~(size_t)255;
    return p;
  };
  float* ACT = (float*)carve((size_t)NN * 2048 * 4);
  unsigned short* Ah = (unsigned short*)carve((size_t)NNP * 1024 * 2);
  unsigned short* Al = (unsigned short*)carve((size_t)NNP * 1024 * 2);
  // weight splits (transposed [N][K] bf16 hi/lo)
  unsigned short* W1h_a = (unsigned short*)carve((size_t)512 * 128 * 2);
  unsigned short* W1l_a = (unsigned short*)carve((size_t)512 * 128 * 2);
  unsigned short* W1h_b = (unsigned short*)carve((size_t)512 * 128 * 2);
  unsigned short* W1l_b = (unsigned short*)carve((size_t)512 * 128 * 2);
  unsigned short* W2h_a = (unsigned short*)carve((size_t)1024 * 512 * 2);
  unsigned short* W2l_a = (unsigned short*)carve((size_t)1024 * 512 * 2);
  unsigned short* W2h_b = (unsigned short*)carve((size_t)1024 * 512 * 2);
  unsigned short* W2l_b = (unsigned short*)carve((size_t)1024 * 512 * 2);
  unsigned short* W3h_a = (unsigned short*)carve((size_t)2048 * 1024 * 2);
  unsigned short* W3l_a = (unsigned short*)carve((size_t)2048 * 1024 * 2);
  unsigned short* W3h_b = (unsigned short*)carve((size_t)2048 * 1024 * 2);
  unsigned short* W3l_b = (unsigned short*)carve((size_t)2048 * 1024 * 2);
  float* P_s  = (float*)carve((size_t)NG * 2048 * 4);
  float* P_t  = (float*)carve((size_t)NG * 2048 * 4);
  float* Z    = (float*)carve((size_t)NG * 2048 * 4);
  float* ZZ   = (float*)carve((size_t)NG * 1024 * 4);
  float* dinv = (float*)carve((size_t)NN * 4);
  int* cnt     = (int*)carve((size_t)NN * 4);
  int* row_ptr = (int*)carve((size_t)(NN + 1) * 4);
  int* cursor  = (int*)carve((size_t)NN * 4);
  int* csr_src = (int*)carve((size_t)NE * 4);
  float* csr_w = (float*)carve((size_t)NE * 4);
  int* seg     = (int*)carve((size_t)(NG + 1) * 4);
  (void)ws_size; (void)n_in; (void)in_sizes; (void)out_size;

  // weight transpose+split (per call; weights are inputs)
  k_wsplit<<<dim3(512 / 32, 128 / 32), 256, 0, stream>>>(W_enc1, W1h_a, W1l_a, 128, 512);
  k_wsplit<<<dim3(512 / 32, 128 / 32), 256, 0, stream>>>(W_enc2, W1h_b, W1l_b, 128, 512);
  k_wsplit<<<dim3(1024 / 32, 512 / 32), 256, 0, stream>>>(W_r1g1, W2h_a, W2l_a, 512, 1024);
  k_wsplit<<<dim3(1024 / 32, 512 / 32), 256, 0, stream>>>(W_r2g1, W2h_b, W2l_b, 512, 1024);
  k_wsplit<<<dim3(2048 / 32, 1024 / 32), 256, 0, stream>>>(W_r1g2, W3h_a, W3l_a, 1024, 2048);
  k_wsplit<<<dim3(2048 / 32, 1024 / 32), 256, 0, stream>>>(W_r2g2, W3h_b, W3l_b, 1024, 2048);

  run_branch(x_s, ei_s, xs_batch, W1h_a, W1l_a, b_enc1, W2h_a, W2l_a, b_r1g1,
             W3h_a, W3l_a, b_r1g2, P_s, ACT, Ah, Al, dinv, cnt, row_ptr, cursor,
             csr_src, csr_w, seg, stream);
  run_branch(x_t, ei_t, xt_batch, W1h_b, W1l_b, b_enc2, W2h_b, W2l_b, b_r2g1,
             W3h_b, W3l_b, b_r2g2, P_t, ACT, Ah, Al, dinv, cnt, row_ptr, cursor,
             csr_src, csr_w, seg, stream);

  // Z = P_s + P_t  [128, 2048]
  k_add<<<(NG * 2048 + 255) / 256, 256, 0, stream>>>(P_s, P_t, Z, NG * 2048);

  // MLP head (fp32; tiny M=128)
  k_gemm<true, false><<<dim3(1024 / 64, (NG + 63) / 64), 256, 0, stream>>>(
      Z, W_l1, b_l1, ZZ, NG, 1024, 2048, nullptr);
  const int OUTN = 1317;
  k_gemm<false, true><<<dim3((OUTN + 63) / 64, (NG + 63) / 64), 256, 0, stream>>>(
      ZZ, W_l2, b_l2, out, NG, OUTN, 1024, out + (size_t)NG * OUTN);
}